// Round 2
// baseline (544.739 us; speedup 1.0000x reference)
//
#include <hip/hip_runtime.h>
#include <cfloat>

#define NROW 32768
#define ZQ_OFF   0
#define LOSS_OFF 8388608
#define PERP_OFF 8388609
#define IDX_OFF  8388610
#define DIST_OFF 8421378

// ws BYTE offsets
#define WSB_WIN     0          // u64[32768] packed (monotone(val)<<32 | k)
#define WSB_ROWNORM 262144     // f32[32768]
#define WSB_EMBNORM 393216     // f32[1024]
#define WSB_IDX     397312     // i32[32768]
#define WSB_COUNTS  528384     // f32[1024]
#define WSB_LOSS    532480     // f32[1]

__device__ __forceinline__ float sq_rn(float x) { return __fmul_rn(x, x); }

__device__ __forceinline__ unsigned enc_f(float f) {
  unsigned u = __float_as_uint(f);
  return (u & 0x80000000u) ? ~u : (u | 0x80000000u);
}
__device__ __forceinline__ float dec_f(unsigned e) {
  unsigned u = (e & 0x80000000u) ? (e ^ 0x80000000u) : ~e;
  return __uint_as_float(u);
}

// numpy pairwise_sum order for 256-length sum of squares:
// split 128+128; each 128: 8 accumulators, ((r0+r1)+(r2+r3))+((r4+r5)+(r6+r7)).
__device__ float pairwise_norm256(const float* __restrict__ p, int stride) {
  float h[2];
#pragma unroll
  for (int half = 0; half < 2; ++half) {
    const float* q = p + (size_t)half * 128 * stride;
    float r[8];
#pragma unroll
    for (int j = 0; j < 8; ++j) r[j] = sq_rn(q[(size_t)j * stride]);
    for (int d8 = 8; d8 < 128; d8 += 8) {
#pragma unroll
      for (int j = 0; j < 8; ++j)
        r[j] = __fadd_rn(r[j], sq_rn(q[(size_t)(d8 + j) * stride]));
    }
    h[half] = __fadd_rn(__fadd_rn(__fadd_rn(r[0], r[1]), __fadd_rn(r[2], r[3])),
                        __fadd_rn(__fadd_rn(r[4], r[5]), __fadd_rn(r[6], r[7])));
  }
  return __fadd_rn(h[0], h[1]);
}

__launch_bounds__(256)
__global__ void embnorm_kernel(const float* __restrict__ emb, float* __restrict__ embnorm) {
  const int k = blockIdx.x * 256 + threadIdx.x;
  embnorm[k] = pairwise_norm256(emb + ((size_t)k << 8), 1);
}

__launch_bounds__(256)
__global__ void rownorm_kernel(const float* __restrict__ z_e, float* __restrict__ rownorm) {
  const int n = blockIdx.x * 256 + threadIdx.x;
  const int b = n >> 10, s = n & 1023;
  rownorm[n] = pairwise_norm256(z_e + ((size_t)b << 18) + s, 1024);
}

// 64x64 tile fp32 distance GEMM. Writes dist and per-row packed min via u64 atomicMin.
__launch_bounds__(256)
__global__ void dist_kernel(const float* __restrict__ z_e, const float* __restrict__ emb,
                            const float* __restrict__ rownorm, const float* __restrict__ embnorm,
                            float* __restrict__ dist, unsigned long long* __restrict__ win) {
  __shared__ float Xs[16][64];
  __shared__ float Es[16][64];
  const int tid = threadIdx.x;
  const int tx = tid & 15, ty = tid >> 4;
  const int li = tid & 63, lq = tid >> 6;
  const int n0 = blockIdx.x << 6;
  const int k0 = blockIdx.y << 6;
  const int bb = n0 >> 10, s0 = n0 & 1023;
  const float* xbase = z_e + ((size_t)bb << 18) + s0;
  float acc[4][4] = {};
  for (int d0 = 0; d0 < 256; d0 += 16) {
#pragma unroll
    for (int u = 0; u < 4; ++u) {
      const int dd = lq + (u << 2);
      Xs[dd][li] = xbase[((size_t)(d0 + dd) << 10) + li];
      Es[dd][li] = emb[((size_t)(k0 + li) << 8) + d0 + dd];
    }
    __syncthreads();
#pragma unroll
    for (int dd = 0; dd < 16; ++dd) {
      const float4 a = *(const float4*)&Xs[dd][ty << 2];
      const float4 e = *(const float4*)&Es[dd][tx << 2];
      const float av[4] = {a.x, a.y, a.z, a.w};
      const float ev[4] = {e.x, e.y, e.z, e.w};
#pragma unroll
      for (int i = 0; i < 4; ++i)
#pragma unroll
        for (int j = 0; j < 4; ++j)
          acc[i][j] = fmaf(av[i], ev[j], acc[i][j]);
    }
    __syncthreads();
  }
  const int kbase = k0 + (tx << 2);
  const float4 env = *(const float4*)(embnorm + kbase);
  const float en[4] = {env.x, env.y, env.z, env.w};
#pragma unroll
  for (int i = 0; i < 4; ++i) {
    const int n = n0 + (ty << 2) + i;
    const float rn = rownorm[n];
    float dv[4];
#pragma unroll
    for (int j = 0; j < 4; ++j) {
      // replicate reference fp32 chain: fl(fl(rn+en) - fl(2*dot))
      dv[j] = __fsub_rn(__fadd_rn(rn, en[j]), __fmul_rn(2.0f, acc[i][j]));
    }
    float* drow = dist + (size_t)n * 1024 + kbase;
    *(float2*)drow = make_float2(dv[0], dv[1]);           // DIST region is 8B-aligned only
    *(float2*)(drow + 2) = make_float2(dv[2], dv[3]);
    // packed (value, index) min: equal value -> smaller k (numpy first-occurrence)
    unsigned long long key = ((unsigned long long)enc_f(dv[0]) << 32) | (unsigned)kbase;
#pragma unroll
    for (int j = 1; j < 4; ++j) {
      const unsigned long long c = ((unsigned long long)enc_f(dv[j]) << 32) | (unsigned)(kbase + j);
      key = (c < key) ? c : key;
    }
#pragma unroll
    for (int mm = 1; mm < 16; mm <<= 1) {
      const unsigned long long o = __shfl_xor(key, mm, 64);
      key = (o < key) ? o : key;
    }
    if (tx == 0) atomicMin(&win[n], key);
  }
}

// Per-row: rescan dist row; all candidates within thr of min get an exactly-rounded
// fl32(fp64 dot) re-evaluation; final argmin with (value, index) order.
__launch_bounds__(256)
__global__ void refine_kernel(const float* __restrict__ z_e, const float* __restrict__ emb,
                              const float* __restrict__ rownorm, const float* __restrict__ embnorm,
                              const float* __restrict__ dist,
                              const unsigned long long* __restrict__ win,
                              int* __restrict__ idx_ws) {
  const int wv = threadIdx.x >> 6, lane = threadIdx.x & 63;
  const int n = (blockIdx.x << 2) + wv;
  const unsigned long long key = win[n];
  const float minv = dec_f((unsigned)(key >> 32));
  const float thr = minv + 2e-4f;
  const int b = n >> 10, s = n & 1023;
  const float* x = z_e + ((size_t)b << 18) + s;
  double xl[4];
#pragma unroll
  for (int u = 0; u < 4; ++u)
    xl[u] = (double)x[((size_t)(lane * 4 + u)) << 10];
  const float rn = rownorm[n];
  float bestv = FLT_MAX;
  int bestk = 0x7fffffff;
  const float* drow = dist + (size_t)n * 1024;
#pragma unroll 1
  for (int j2 = 0; j2 < 8; ++j2) {
    const float2 dd = *(const float2*)(drow + lane * 16 + j2 * 2);
#pragma unroll 1
    for (int j = 0; j < 2; ++j) {
      const float d = j ? dd.y : dd.x;
      unsigned long long m = __ballot(d <= thr);
      while (m) {
        const int l = __ffsll(m) - 1;
        m &= m - 1;
        const int kk = l * 16 + j2 * 2 + j;
        const float* e = emb + ((size_t)kk << 8) + lane * 4;
        double p = xl[0] * (double)e[0] + xl[1] * (double)e[1]
                 + xl[2] * (double)e[2] + xl[3] * (double)e[3];
#pragma unroll
        for (int mm = 32; mm; mm >>= 1) p += __shfl_xor(p, mm, 64);
        const float dotf = (float)p;                       // fl32(exact dot)
        const float D = __fsub_rn(__fadd_rn(rn, embnorm[kk]), __fmul_rn(2.0f, dotf));
        if (D < bestv || (D == bestv && kk < bestk)) { bestv = D; bestk = kk; }
      }
    }
  }
  if (lane == 0) idx_ws[n] = bestk;
}

__launch_bounds__(256)
__global__ void idxout_kernel(const int* __restrict__ idx_ws, float* __restrict__ out,
                              float* __restrict__ counts) {
  const int n = blockIdx.x * 256 + threadIdx.x;
  const int ii = idx_ws[n];
  out[IDX_OFF + n] = (float)ii;
  atomicAdd(&counts[ii], 1.0f);
}

__launch_bounds__(256)
__global__ void zqloss_kernel(const float* __restrict__ z_e, const float* __restrict__ emb,
                              const int* __restrict__ idx_ws, float* __restrict__ out,
                              float* __restrict__ lossacc) {
  const size_t o = ((size_t)blockIdx.x * 256 + threadIdx.x) * 4;
  const int b = (int)(o >> 18);
  const int d = ((int)(o >> 10)) & 255;
  const int s = (int)o & 1023;
  const int n = (b << 10) + s;
  const float4 z = *(const float4*)(z_e + o);
  const int4 iv = *(const int4*)(idx_ws + n);
  const float zz[4] = {z.x, z.y, z.z, z.w};
  float zq[4];
  zq[0] = emb[((size_t)iv.x << 8) + d];
  zq[1] = emb[((size_t)iv.y << 8) + d];
  zq[2] = emb[((size_t)iv.z << 8) + d];
  zq[3] = emb[((size_t)iv.w << 8) + d];
  float4 ov;
  float* ovp = (float*)&ov;
  float lsum = 0.f;
#pragma unroll
  for (int j = 0; j < 4; ++j) {
    const float diff = __fsub_rn(zq[j], zz[j]);
    ovp[j] = __fadd_rn(zz[j], diff);                       // z + (z_q - z)
    lsum = fmaf(diff, diff, lsum);
  }
  *(float4*)(out + ZQ_OFF + o) = ov;
#pragma unroll
  for (int m = 32; m > 0; m >>= 1) lsum += __shfl_xor(lsum, m, 64);
  __shared__ float wred[4];
  if ((threadIdx.x & 63) == 0) wred[threadIdx.x >> 6] = lsum;
  __syncthreads();
  if (threadIdx.x == 0) atomicAdd(lossacc, wred[0] + wred[1] + wred[2] + wred[3]);
}

__launch_bounds__(256)
__global__ void final_kernel(const float* __restrict__ counts, const float* __restrict__ lossacc,
                             float* __restrict__ out) {
  const int t = threadIdx.x;
  float ssum = 0.f;
#pragma unroll
  for (int u = 0; u < 4; ++u) {
    const float p = counts[t * 4 + u] * (1.0f / 32768.0f);
    ssum += p * logf(p + 1e-10f);
  }
#pragma unroll
  for (int m = 32; m > 0; m >>= 1) ssum += __shfl_xor(ssum, m, 64);
  __shared__ float wred[4];
  if ((t & 63) == 0) wred[t >> 6] = ssum;
  __syncthreads();
  if (t == 0) {
    const float tot = wred[0] + wred[1] + wred[2] + wred[3];
    out[PERP_OFF] = expf(-tot);
    const float mql = lossacc[0] * (1.0f / 8388608.0f);
    out[LOSS_OFF] = __fadd_rn(mql, __fmul_rn(0.25f, mql));  // q_loss + 0.25*e_loss
  }
}

extern "C" void kernel_launch(void* const* d_in, const int* in_sizes, int n_in,
                              void* d_out, int out_size, void* d_ws, size_t ws_size,
                              hipStream_t stream) {
  const float* z_e = (const float*)d_in[0];
  const float* emb = (const float*)d_in[1];
  float* out = (float*)d_out;
  char* ws = (char*)d_ws;

  unsigned long long* win = (unsigned long long*)(ws + WSB_WIN);
  float* rownorm = (float*)(ws + WSB_ROWNORM);
  float* embnorm = (float*)(ws + WSB_EMBNORM);
  int* idx_ws = (int*)(ws + WSB_IDX);
  float* counts = (float*)(ws + WSB_COUNTS);
  float* lossacc = (float*)(ws + WSB_LOSS);

  hipMemsetAsync(win, 0xFF, NROW * 8, stream);
  hipMemsetAsync(counts, 0, 1025 * 4, stream);

  hipLaunchKernelGGL(embnorm_kernel, dim3(4), dim3(256), 0, stream, emb, embnorm);
  hipLaunchKernelGGL(rownorm_kernel, dim3(128), dim3(256), 0, stream, z_e, rownorm);
  hipLaunchKernelGGL(dist_kernel, dim3(512, 16), dim3(256), 0, stream,
                     z_e, emb, rownorm, embnorm, out + DIST_OFF, win);
  hipLaunchKernelGGL(refine_kernel, dim3(8192), dim3(256), 0, stream,
                     z_e, emb, rownorm, embnorm, out + DIST_OFF, win, idx_ws);
  hipLaunchKernelGGL(idxout_kernel, dim3(128), dim3(256), 0, stream, idx_ws, out, counts);
  hipLaunchKernelGGL(zqloss_kernel, dim3(8192), dim3(256), 0, stream,
                     z_e, emb, idx_ws, out, lossacc);
  hipLaunchKernelGGL(final_kernel, dim3(1), dim3(256), 0, stream, counts, lossacc, out);
}

// Round 3
// 278.570 us; speedup vs baseline: 1.9555x; 1.9555x over previous
//
#include <hip/hip_runtime.h>
#include <cfloat>

typedef __attribute__((ext_vector_type(8))) short bf16x8;
typedef __attribute__((ext_vector_type(4))) float f32x4;
typedef __attribute__((ext_vector_type(8))) unsigned short u16x8;

#define NROW 32768
#define ZQ_OFF   0
#define LOSS_OFF 8388608
#define PERP_OFF 8388609
#define IDX_OFF  8388610
#define DIST_OFF 8421378

// ws byte offsets
#define WSB_AHI  0x0
#define WSB_ALO  0x1000000
#define WSB_BHI  0x2000000
#define WSB_BLO  0x2080000
#define WSB_RN   0x2100000
#define WSB_EN   0x2120000
#define WSB_PKEY 0x2200000
#define WSB_IDX  0x2600000
#define WSB_CNT  0x2620000
#define WSB_LOSS 0x2621000

__device__ __forceinline__ float sq_rn(float x) { return __fmul_rn(x, x); }

__device__ __forceinline__ unsigned enc_f(float f) {
  unsigned u = __float_as_uint(f);
  return (u & 0x80000000u) ? ~u : (u | 0x80000000u);
}
__device__ __forceinline__ float dec_f(unsigned e) {
  unsigned u = (e & 0x80000000u) ? (e ^ 0x80000000u) : ~e;
  return __uint_as_float(u);
}

__device__ __forceinline__ unsigned short bf16_rne(float f) {
  unsigned u = __float_as_uint(f);
  unsigned r = u + 0x7fffu + ((u >> 16) & 1u);
  return (unsigned short)(r >> 16);
}

__device__ __forceinline__ void gload16(const void* g, void* l) {
  __builtin_amdgcn_global_load_lds(
      (const __attribute__((address_space(1))) unsigned int*)g,
      (__attribute__((address_space(3))) unsigned int*)l, 16, 0, 0);
}

// numpy pairwise_sum order for 256-length sum of squares (load-bearing: feeds the
// big part of the distance chain; must match np bit-exactly).
__device__ float pairwise_norm256(const float* __restrict__ p, int stride) {
  float h[2];
#pragma unroll
  for (int half = 0; half < 2; ++half) {
    const float* q = p + (size_t)half * 128 * stride;
    float r[8];
#pragma unroll
    for (int j = 0; j < 8; ++j) r[j] = sq_rn(q[(size_t)j * stride]);
    for (int d8 = 8; d8 < 128; d8 += 8) {
#pragma unroll
      for (int j = 0; j < 8; ++j)
        r[j] = __fadd_rn(r[j], sq_rn(q[(size_t)(d8 + j) * stride]));
    }
    h[half] = __fadd_rn(__fadd_rn(__fadd_rn(r[0], r[1]), __fadd_rn(r[2], r[3])),
                        __fadd_rn(__fadd_rn(r[4], r[5]), __fadd_rn(r[6], r[7])));
  }
  return __fadd_rn(h[0], h[1]);
}

__launch_bounds__(256)
__global__ void embnorm_kernel(const float* __restrict__ emb, float* __restrict__ embnorm) {
  const int k = blockIdx.x * 256 + threadIdx.x;
  embnorm[k] = pairwise_norm256(emb + ((size_t)k << 8), 1);
}

__launch_bounds__(256)
__global__ void rownorm_kernel(const float* __restrict__ z_e, float* __restrict__ rownorm) {
  const int n = blockIdx.x * 256 + threadIdx.x;
  const int b = n >> 10, s = n & 1023;
  rownorm[n] = pairwise_norm256(z_e + ((size_t)b << 18) + s, 1024);
}

// Transpose z_e [b][d][s] -> pre-swizzled hi/lo bf16 planes keyed for linear
// global_load_lds staging: chunk (ntile, stage=dt, q = row*8 + (c ^ (row&7)))
__launch_bounds__(256)
__global__ void prepA_kernel(const float* __restrict__ z_e,
                             unsigned short* __restrict__ ahi,
                             unsigned short* __restrict__ alo) {
  __shared__ float xt[64][68];
  const int t = threadIdx.x;
  const int blk = blockIdx.x;          // b*64 + dt*16 + st
  const int b  = blk >> 6;
  const int dt = (blk >> 4) & 3;       // 64-d tile == stage index
  const int st = blk & 15;             // 64-s tile
  const int d0 = dt << 6, s0 = st << 6;
  const size_t zbase = ((size_t)b << 18) + ((size_t)d0 << 10) + s0;
  {
    const int dd0 = t >> 4;
    const int s4 = (t & 15) << 2;
#pragma unroll
    for (int p = 0; p < 4; ++p) {
      const int dd = p * 16 + dd0;
      const float4 v = *(const float4*)(z_e + zbase + ((size_t)dd << 10) + s4);
      const int sw = ((dd >> 3) & 3) << 3;     // LDS bank swizzle on s index
      *(float4*)(&xt[dd][s4 ^ sw]) = v;
    }
  }
  __syncthreads();
  const int r0 = t >> 3;   // 0..31
  const int c  = t & 7;    // d-octet within tile
#pragma unroll
  for (int p = 0; p < 2; ++p) {
    const int r = p * 32 + r0;                 // s-local row
    const int n = (b << 10) + s0 + r;          // global row
    u16x8 vh, vl;
#pragma unroll
    for (int u = 0; u < 8; ++u) {
      const int d = c * 8 + u;
      const int sw = ((d >> 3) & 3) << 3;      // == (c&3)<<3
      const float x = xt[d][r ^ sw];
      const unsigned short h = bf16_rne(x);
      vh[u] = (short)h;
      vl[u] = (short)bf16_rne(x - __uint_as_float((unsigned)h << 16));
    }
    const size_t pos = (((size_t)(n >> 7)) << 12) + ((size_t)dt << 10)
                     + ((size_t)(n & 127) << 3) + (size_t)(c ^ (n & 7));
    *(u16x8*)(ahi + pos * 8) = vh;
    *(u16x8*)(alo + pos * 8) = vl;
  }
}

__launch_bounds__(256)
__global__ void prepB_kernel(const float* __restrict__ emb,
                             unsigned short* __restrict__ bhi,
                             unsigned short* __restrict__ blo) {
  const int tg = blockIdx.x * 256 + threadIdx.x;   // 32768
  const int k = tg >> 5, cd = tg & 31;
  const float4 v0 = *(const float4*)(emb + ((size_t)k << 8) + cd * 8);
  const float4 v1 = *(const float4*)(emb + ((size_t)k << 8) + cd * 8 + 4);
  const float xs[8] = {v0.x, v0.y, v0.z, v0.w, v1.x, v1.y, v1.z, v1.w};
  u16x8 vh, vl;
#pragma unroll
  for (int u = 0; u < 8; ++u) {
    const unsigned short h = bf16_rne(xs[u]);
    vh[u] = (short)h;
    vl[u] = (short)bf16_rne(xs[u] - __uint_as_float((unsigned)h << 16));
  }
  const size_t pos = (((size_t)(k >> 7)) << 12) + ((size_t)(cd >> 3) << 10)
                   + ((size_t)(k & 127) << 3) + (size_t)((cd & 7) ^ (k & 7));
  *(u16x8*)(bhi + pos * 8) = vh;
  *(u16x8*)(blo + pos * 8) = vl;
}

#define LDS_AHI 0
#define LDS_ALO 16384
#define LDS_BHI 32768
#define LDS_BLO 49152

// 128x128 tile, 4 waves of 64x64, bf16x3 MFMA. Writes dist + per-(row,64tile) pkey.
__launch_bounds__(256, 2)
__global__ void dist_kernel(const unsigned short* __restrict__ ahi,
                            const unsigned short* __restrict__ alo,
                            const unsigned short* __restrict__ bhi,
                            const unsigned short* __restrict__ blo,
                            const float* __restrict__ rownorm,
                            const float* __restrict__ embnorm,
                            float* __restrict__ dist,
                            unsigned long long* __restrict__ pkey) {
  __shared__ char lds[65536];
  const int tid = threadIdx.x;
  const int lane = tid & 63;
  const int wv = tid >> 6;
  const int wr = wv >> 1, wc = wv & 1;
  const int ntile = blockIdx.x, ktile = blockIdx.y;

  const unsigned short* gsrc =
      (wv == 0) ? ahi + ((size_t)ntile << 15) :
      (wv == 1) ? alo + ((size_t)ntile << 15) :
      (wv == 2) ? bhi + ((size_t)ktile << 15) :
                  blo + ((size_t)ktile << 15);
  char* ldsArr = lds + (wv << 14);

  f32x4 acc[4][4];
#pragma unroll
  for (int i = 0; i < 4; ++i)
#pragma unroll
    for (int j = 0; j < 4; ++j) acc[i][j] = (f32x4){0.f, 0.f, 0.f, 0.f};

  for (int s = 0; s < 4; ++s) {
    {
      const unsigned short* g = gsrc + ((size_t)s << 13);
#pragma unroll
      for (int q = 0; q < 16; ++q)
        gload16(g + (((size_t)(q * 64 + lane)) << 3), ldsArr + q * 1024);
    }
    __syncthreads();
#pragma unroll
    for (int half = 0; half < 2; ++half) {
      const int kb = half << 2;
      bf16x8 ah[4], al[4], bh[4], bl[4];
#pragma unroll
      for (int i = 0; i < 4; ++i) {
        const int row = (wr << 6) + (i << 4) + (lane & 15);
        const int ch = (kb + (lane >> 4)) ^ (row & 7);
        ah[i] = *(const bf16x8*)(lds + LDS_AHI + ((row << 3) + ch) * 16);
        al[i] = *(const bf16x8*)(lds + LDS_ALO + ((row << 3) + ch) * 16);
      }
#pragma unroll
      for (int j = 0; j < 4; ++j) {
        const int row = (wc << 6) + (j << 4) + (lane & 15);
        const int ch = (kb + (lane >> 4)) ^ (row & 7);
        bh[j] = *(const bf16x8*)(lds + LDS_BHI + ((row << 3) + ch) * 16);
        bl[j] = *(const bf16x8*)(lds + LDS_BLO + ((row << 3) + ch) * 16);
      }
#pragma unroll
      for (int i = 0; i < 4; ++i)
#pragma unroll
        for (int j = 0; j < 4; ++j) {
          acc[i][j] = __builtin_amdgcn_mfma_f32_16x16x32_bf16(al[i], bh[j], acc[i][j], 0, 0, 0);
          acc[i][j] = __builtin_amdgcn_mfma_f32_16x16x32_bf16(ah[i], bl[j], acc[i][j], 0, 0, 0);
          acc[i][j] = __builtin_amdgcn_mfma_f32_16x16x32_bf16(ah[i], bh[j], acc[i][j], 0, 0, 0);
        }
    }
    __syncthreads();
  }
  // epilogue: reference fp32 chain, dist store, per-(row,64tile) packed min
  const int n0 = (ntile << 7) + (wr << 6);
  const int k0 = (ktile << 7) + (wc << 6);
  const int g = lane >> 4, tl = lane & 15;
  const int tileidx = (ktile << 1) + wc;
  float en[4];
#pragma unroll
  for (int j = 0; j < 4; ++j) en[j] = embnorm[k0 + (j << 4) + tl];
#pragma unroll
  for (int i = 0; i < 4; ++i) {
#pragma unroll
    for (int r = 0; r < 4; ++r) {
      const int n = n0 + (i << 4) + (g << 2) + r;
      const float rn = rownorm[n];
      float* drow = dist + (size_t)n * 1024 + k0 + tl;
      unsigned long long key = ~0ULL;
#pragma unroll
      for (int j = 0; j < 4; ++j) {
        const float dv = __fsub_rn(__fadd_rn(rn, en[j]), __fmul_rn(2.0f, acc[i][j][r]));
        drow[j << 4] = dv;
        const unsigned long long c =
            ((unsigned long long)enc_f(dv) << 32) | (unsigned)(k0 + (j << 4) + tl);
        key = c < key ? c : key;
      }
#pragma unroll
      for (int mm = 1; mm < 16; mm <<= 1) {
        const unsigned long long o = __shfl_xor(key, mm, 64);
        key = o < key ? o : key;
      }
      if (tl == 0) pkey[(size_t)n * 16 + tileidx] = key;
    }
  }
}

// One wave per row: merge 16 partials, rescan qualifying 64-tiles, exact fp64-dot
// re-evaluation of candidates within window; first-index tie-break. Also emits
// index output + histogram.
__launch_bounds__(256)
__global__ void refine_kernel(const float* __restrict__ z_e,
                              const float* __restrict__ emb,
                              const float* __restrict__ rownorm,
                              const float* __restrict__ embnorm,
                              const float* __restrict__ dist,
                              const unsigned long long* __restrict__ pkey,
                              int* __restrict__ idx_ws,
                              float* __restrict__ out,
                              float* __restrict__ counts) {
  __shared__ float xl[16][260];
  const int t = threadIdx.x;
  const int s0 = blockIdx.x << 4;
  const int b = s0 >> 10, sb = s0 & 1023;
  {
    const int d = t >> 2;
    const int s4 = (t & 3) << 2;
#pragma unroll
    for (int p = 0; p < 4; ++p) {
      const int dd = d + p * 64;
      const float4 v = *(const float4*)(z_e + ((size_t)b << 18) + ((size_t)dd << 10) + sb + s4);
      xl[s4 + 0][dd] = v.x; xl[s4 + 1][dd] = v.y;
      xl[s4 + 2][dd] = v.z; xl[s4 + 3][dd] = v.w;
    }
  }
  __syncthreads();
  const int wv = t >> 6, lane = t & 63;
  for (int rr = 0; rr < 4; ++rr) {
    const int srow = (wv << 2) + rr;
    const int n = s0 + srow;
    const unsigned long long mypk = (lane < 16) ? pkey[(size_t)n * 16 + lane] : ~0ULL;
    unsigned long long key = mypk;
#pragma unroll
    for (int mm = 1; mm < 64; mm <<= 1) {
      const unsigned long long o = __shfl_xor(key, mm, 64);
      key = o < key ? o : key;
    }
    const float v1 = dec_f((unsigned)(key >> 32));
    const unsigned ue = (__float_as_uint(v1) >> 23) & 0xffu;
    const float ulp = __uint_as_float((ue - 23) << 23);
    const float w = v1 + 2.0f * ulp + 8e-6f;
    unsigned qmask = (unsigned)(__ballot(dec_f((unsigned)(mypk >> 32)) <= w) & 0xffffULL);
    const float rn = rownorm[n];
    const float4 xv = *(const float4*)(&xl[srow][lane << 2]);
    unsigned long long best = ~0ULL;
    while (qmask) {
      const int T = __ffs(qmask) - 1;
      qmask &= qmask - 1;
      const float dval = dist[(size_t)n * 1024 + T * 64 + lane];
      unsigned long long cm = __ballot(dval <= w);
      while (cm) {
        const int l2 = __ffsll(cm) - 1;
        cm &= cm - 1;
        const int kk = T * 64 + l2;
        const float4 ev = *(const float4*)(emb + ((size_t)kk << 8) + (lane << 2));
        double p = (double)xv.x * ev.x + (double)xv.y * ev.y
                 + (double)xv.z * ev.z + (double)xv.w * ev.w;
#pragma unroll
        for (int mm = 1; mm < 64; mm <<= 1) p += __shfl_xor(p, mm, 64);
        const float dotf = (float)p;
        const float D = __fsub_rn(__fadd_rn(rn, embnorm[kk]), __fmul_rn(2.0f, dotf));
        const unsigned long long c = ((unsigned long long)enc_f(D) << 32) | (unsigned)kk;
        best = c < best ? c : best;
      }
    }
    const int bestk = (int)(best & 0xffffffffu);
    if (lane == 0) {
      idx_ws[n] = bestk;
      out[IDX_OFF + n] = (float)bestk;
      atomicAdd(&counts[bestk], 1.0f);
    }
  }
}

__launch_bounds__(256)
__global__ void zqloss_kernel(const float* __restrict__ z_e, const float* __restrict__ emb,
                              const int* __restrict__ idx_ws, float* __restrict__ out,
                              float* __restrict__ lossacc) {
  const size_t o = ((size_t)blockIdx.x * 256 + threadIdx.x) * 4;
  const int b = (int)(o >> 18);
  const int d = ((int)(o >> 10)) & 255;
  const int s = (int)o & 1023;
  const int n = (b << 10) + s;
  const float4 z = *(const float4*)(z_e + o);
  const int4 iv = *(const int4*)(idx_ws + n);
  const float zz[4] = {z.x, z.y, z.z, z.w};
  float zq[4];
  zq[0] = emb[((size_t)iv.x << 8) + d];
  zq[1] = emb[((size_t)iv.y << 8) + d];
  zq[2] = emb[((size_t)iv.z << 8) + d];
  zq[3] = emb[((size_t)iv.w << 8) + d];
  float4 ov;
  float* ovp = (float*)&ov;
  float lsum = 0.f;
#pragma unroll
  for (int j = 0; j < 4; ++j) {
    const float diff = __fsub_rn(zq[j], zz[j]);
    ovp[j] = __fadd_rn(zz[j], diff);
    lsum = fmaf(diff, diff, lsum);
  }
  *(float4*)(out + ZQ_OFF + o) = ov;
#pragma unroll
  for (int m = 32; m > 0; m >>= 1) lsum += __shfl_xor(lsum, m, 64);
  __shared__ float wred[4];
  if ((threadIdx.x & 63) == 0) wred[threadIdx.x >> 6] = lsum;
  __syncthreads();
  if (threadIdx.x == 0) atomicAdd(lossacc, wred[0] + wred[1] + wred[2] + wred[3]);
}

__launch_bounds__(256)
__global__ void final_kernel(const float* __restrict__ counts, const float* __restrict__ lossacc,
                             float* __restrict__ out) {
  const int t = threadIdx.x;
  float ssum = 0.f;
#pragma unroll
  for (int u = 0; u < 4; ++u) {
    const float p = counts[t * 4 + u] * (1.0f / 32768.0f);
    ssum += p * logf(p + 1e-10f);
  }
#pragma unroll
  for (int m = 32; m > 0; m >>= 1) ssum += __shfl_xor(ssum, m, 64);
  __shared__ float wred[4];
  if ((t & 63) == 0) wred[t >> 6] = ssum;
  __syncthreads();
  if (t == 0) {
    const float tot = wred[0] + wred[1] + wred[2] + wred[3];
    out[PERP_OFF] = expf(-tot);
    const float mql = lossacc[0] * (1.0f / 8388608.0f);
    out[LOSS_OFF] = __fadd_rn(mql, __fmul_rn(0.25f, mql));
  }
}

extern "C" void kernel_launch(void* const* d_in, const int* in_sizes, int n_in,
                              void* d_out, int out_size, void* d_ws, size_t ws_size,
                              hipStream_t stream) {
  const float* z_e = (const float*)d_in[0];
  const float* emb = (const float*)d_in[1];
  float* out = (float*)d_out;
  char* ws = (char*)d_ws;

  unsigned short* ahi = (unsigned short*)(ws + WSB_AHI);
  unsigned short* alo = (unsigned short*)(ws + WSB_ALO);
  unsigned short* bhi = (unsigned short*)(ws + WSB_BHI);
  unsigned short* blo = (unsigned short*)(ws + WSB_BLO);
  float* rownorm = (float*)(ws + WSB_RN);
  float* embnorm = (float*)(ws + WSB_EN);
  unsigned long long* pkey = (unsigned long long*)(ws + WSB_PKEY);
  int* idx_ws = (int*)(ws + WSB_IDX);
  float* counts = (float*)(ws + WSB_CNT);
  float* lossacc = (float*)(ws + WSB_LOSS);

  hipMemsetAsync(ws + WSB_CNT, 0, 4100, stream);

  hipLaunchKernelGGL(embnorm_kernel, dim3(4), dim3(256), 0, stream, emb, embnorm);
  hipLaunchKernelGGL(rownorm_kernel, dim3(128), dim3(256), 0, stream, z_e, rownorm);
  hipLaunchKernelGGL(prepA_kernel, dim3(2048), dim3(256), 0, stream, z_e, ahi, alo);
  hipLaunchKernelGGL(prepB_kernel, dim3(128), dim3(256), 0, stream, emb, bhi, blo);
  hipLaunchKernelGGL(dist_kernel, dim3(256, 8), dim3(256), 0, stream,
                     ahi, alo, bhi, blo, rownorm, embnorm, out + DIST_OFF, pkey);
  hipLaunchKernelGGL(refine_kernel, dim3(2048), dim3(256), 0, stream,
                     z_e, emb, rownorm, embnorm, out + DIST_OFF, pkey, idx_ws, out, counts);
  hipLaunchKernelGGL(zqloss_kernel, dim3(8192), dim3(256), 0, stream,
                     z_e, emb, idx_ws, out, lossacc);
  hipLaunchKernelGGL(final_kernel, dim3(1), dim3(256), 0, stream, counts, lossacc, out);
}

// Round 4
// 188.196 us; speedup vs baseline: 2.8945x; 1.4802x over previous
//
#include <hip/hip_runtime.h>
#include <cfloat>

typedef __attribute__((ext_vector_type(8))) short bf16x8;
typedef __attribute__((ext_vector_type(4))) float f32x4;
typedef __attribute__((ext_vector_type(8))) unsigned short u16x8;

#define NROW 32768
#define ZQ_OFF   0
#define LOSS_OFF 8388608
#define PERP_OFF 8388609
#define IDX_OFF  8388610
#define DIST_OFF 8421378

// ws byte offsets
#define WSB_AHI  0x0
#define WSB_ALO  0x1000000
#define WSB_BHI  0x2000000
#define WSB_BLO  0x2080000
#define WSB_RN   0x2100000
#define WSB_EN   0x2120000
#define WSB_PKEY 0x2200000
#define WSB_IDX  0x2600000
#define WSB_CNT  0x2620000
#define WSB_LOSS 0x2621000

__device__ __forceinline__ float sq_rn(float x) { return __fmul_rn(x, x); }

__device__ __forceinline__ unsigned enc_f(float f) {
  unsigned u = __float_as_uint(f);
  return (u & 0x80000000u) ? ~u : (u | 0x80000000u);
}
__device__ __forceinline__ float dec_f(unsigned e) {
  unsigned u = (e & 0x80000000u) ? (e ^ 0x80000000u) : ~e;
  return __uint_as_float(u);
}

__device__ __forceinline__ unsigned short bf16_rne(float f) {
  unsigned u = __float_as_uint(f);
  unsigned r = u + 0x7fffu + ((u >> 16) & 1u);
  return (unsigned short)(r >> 16);
}

__device__ __forceinline__ void gload16(const void* g, void* l) {
  __builtin_amdgcn_global_load_lds(
      (const __attribute__((address_space(1))) unsigned int*)g,
      (__attribute__((address_space(3))) unsigned int*)l, 16, 0, 0);
}

// numpy pairwise_sum order for 256-length sum of squares (load-bearing: feeds the
// big part of the distance chain; must match np bit-exactly).
__device__ float pairwise_norm256(const float* __restrict__ p, int stride) {
  float h[2];
#pragma unroll
  for (int half = 0; half < 2; ++half) {
    const float* q = p + (size_t)half * 128 * stride;
    float r[8];
#pragma unroll
    for (int j = 0; j < 8; ++j) r[j] = sq_rn(q[(size_t)j * stride]);
    for (int d8 = 8; d8 < 128; d8 += 8) {
#pragma unroll
      for (int j = 0; j < 8; ++j)
        r[j] = __fadd_rn(r[j], sq_rn(q[(size_t)(d8 + j) * stride]));
    }
    h[half] = __fadd_rn(__fadd_rn(__fadd_rn(r[0], r[1]), __fadd_rn(r[2], r[3])),
                        __fadd_rn(__fadd_rn(r[4], r[5]), __fadd_rn(r[6], r[7])));
  }
  return __fadd_rn(h[0], h[1]);
}

__launch_bounds__(256)
__global__ void embnorm_kernel(const float* __restrict__ emb, float* __restrict__ embnorm) {
  const int k = blockIdx.x * 256 + threadIdx.x;
  embnorm[k] = pairwise_norm256(emb + ((size_t)k << 8), 1);
}

__launch_bounds__(256)
__global__ void rownorm_kernel(const float* __restrict__ z_e, float* __restrict__ rownorm) {
  const int n = blockIdx.x * 256 + threadIdx.x;
  const int b = n >> 10, s = n & 1023;
  rownorm[n] = pairwise_norm256(z_e + ((size_t)b << 18) + s, 1024);
}

// Transpose z_e [b][d][s] -> pre-swizzled hi/lo bf16 planes keyed for linear
// global_load_lds staging: chunk (ntile, stage=dt, q = row*8 + (c ^ (row&7)))
__launch_bounds__(256)
__global__ void prepA_kernel(const float* __restrict__ z_e,
                             unsigned short* __restrict__ ahi,
                             unsigned short* __restrict__ alo) {
  __shared__ float xt[64][68];
  const int t = threadIdx.x;
  const int blk = blockIdx.x;          // b*64 + dt*16 + st
  const int b  = blk >> 6;
  const int dt = (blk >> 4) & 3;       // 64-d tile == stage index
  const int st = blk & 15;             // 64-s tile
  const int d0 = dt << 6, s0 = st << 6;
  const size_t zbase = ((size_t)b << 18) + ((size_t)d0 << 10) + s0;
  {
    const int dd0 = t >> 4;
    const int s4 = (t & 15) << 2;
#pragma unroll
    for (int p = 0; p < 4; ++p) {
      const int dd = p * 16 + dd0;
      const float4 v = *(const float4*)(z_e + zbase + ((size_t)dd << 10) + s4);
      const int sw = ((dd >> 3) & 3) << 3;     // LDS bank swizzle on s index
      *(float4*)(&xt[dd][s4 ^ sw]) = v;
    }
  }
  __syncthreads();
  const int r0 = t >> 3;   // 0..31
  const int c  = t & 7;    // d-octet within tile
#pragma unroll
  for (int p = 0; p < 2; ++p) {
    const int r = p * 32 + r0;                 // s-local row
    const int n = (b << 10) + s0 + r;          // global row
    u16x8 vh, vl;
#pragma unroll
    for (int u = 0; u < 8; ++u) {
      const int d = c * 8 + u;
      const int sw = ((d >> 3) & 3) << 3;      // == (c&3)<<3
      const float x = xt[d][r ^ sw];
      const unsigned short h = bf16_rne(x);
      vh[u] = (short)h;
      vl[u] = (short)bf16_rne(x - __uint_as_float((unsigned)h << 16));
    }
    const size_t pos = (((size_t)(n >> 7)) << 12) + ((size_t)dt << 10)
                     + ((size_t)(n & 127) << 3) + (size_t)(c ^ (n & 7));
    *(u16x8*)(ahi + pos * 8) = vh;
    *(u16x8*)(alo + pos * 8) = vl;
  }
}

__launch_bounds__(256)
__global__ void prepB_kernel(const float* __restrict__ emb,
                             unsigned short* __restrict__ bhi,
                             unsigned short* __restrict__ blo) {
  const int tg = blockIdx.x * 256 + threadIdx.x;   // 32768
  const int k = tg >> 5, cd = tg & 31;
  const float4 v0 = *(const float4*)(emb + ((size_t)k << 8) + cd * 8);
  const float4 v1 = *(const float4*)(emb + ((size_t)k << 8) + cd * 8 + 4);
  const float xs[8] = {v0.x, v0.y, v0.z, v0.w, v1.x, v1.y, v1.z, v1.w};
  u16x8 vh, vl;
#pragma unroll
  for (int u = 0; u < 8; ++u) {
    const unsigned short h = bf16_rne(xs[u]);
    vh[u] = (short)h;
    vl[u] = (short)bf16_rne(xs[u] - __uint_as_float((unsigned)h << 16));
  }
  const size_t pos = (((size_t)(k >> 7)) << 12) + ((size_t)(cd >> 3) << 10)
                   + ((size_t)(k & 127) << 3) + (size_t)((cd & 7) ^ (k & 7));
  *(u16x8*)(bhi + pos * 8) = vh;
  *(u16x8*)(blo + pos * 8) = vl;
}

#define LDS_AHI 0
#define LDS_ALO 16384
#define LDS_BHI 32768
#define LDS_BLO 49152

// 128x128 tile, 4 waves of 64x64, bf16x3 MFMA. Writes dist + per-(row,64tile) pkey.
// Flattened grid (2048) with XCD-chunked mapping: each XCD runs 32 ntiles with all
// 8 ktiles back-to-back so the A-tile is L2-resident for 7 of its 8 uses.
__launch_bounds__(256, 2)
__global__ void dist_kernel(const unsigned short* __restrict__ ahi,
                            const unsigned short* __restrict__ alo,
                            const unsigned short* __restrict__ bhi,
                            const unsigned short* __restrict__ blo,
                            const float* __restrict__ rownorm,
                            const float* __restrict__ embnorm,
                            float* __restrict__ dist,
                            unsigned long long* __restrict__ pkey) {
  __shared__ char lds[65536];
  const int tid = threadIdx.x;
  const int lane = tid & 63;
  const int wv = tid >> 6;
  const int wr = wv >> 1, wc = wv & 1;
  const int bid = blockIdx.x;
  const int xcd = bid & 7;
  const int jj = bid >> 3;
  const int ntile = (xcd << 5) + (jj >> 3);
  const int ktile = jj & 7;

  const unsigned short* gsrc =
      (wv == 0) ? ahi + ((size_t)ntile << 15) :
      (wv == 1) ? alo + ((size_t)ntile << 15) :
      (wv == 2) ? bhi + ((size_t)ktile << 15) :
                  blo + ((size_t)ktile << 15);
  char* ldsArr = lds + (wv << 14);

  f32x4 acc[4][4];
#pragma unroll
  for (int i = 0; i < 4; ++i)
#pragma unroll
    for (int j = 0; j < 4; ++j) acc[i][j] = (f32x4){0.f, 0.f, 0.f, 0.f};

  for (int s = 0; s < 4; ++s) {
    {
      const unsigned short* g = gsrc + ((size_t)s << 13);
#pragma unroll
      for (int q = 0; q < 16; ++q)
        gload16(g + (((size_t)(q * 64 + lane)) << 3), ldsArr + q * 1024);
    }
    __syncthreads();
#pragma unroll
    for (int half = 0; half < 2; ++half) {
      const int kb = half << 2;
      bf16x8 ah[4], al[4], bh[4], bl[4];
#pragma unroll
      for (int i = 0; i < 4; ++i) {
        const int row = (wr << 6) + (i << 4) + (lane & 15);
        const int ch = (kb + (lane >> 4)) ^ (row & 7);
        ah[i] = *(const bf16x8*)(lds + LDS_AHI + ((row << 3) + ch) * 16);
        al[i] = *(const bf16x8*)(lds + LDS_ALO + ((row << 3) + ch) * 16);
      }
#pragma unroll
      for (int j = 0; j < 4; ++j) {
        const int row = (wc << 6) + (j << 4) + (lane & 15);
        const int ch = (kb + (lane >> 4)) ^ (row & 7);
        bh[j] = *(const bf16x8*)(lds + LDS_BHI + ((row << 3) + ch) * 16);
        bl[j] = *(const bf16x8*)(lds + LDS_BLO + ((row << 3) + ch) * 16);
      }
#pragma unroll
      for (int i = 0; i < 4; ++i)
#pragma unroll
        for (int j = 0; j < 4; ++j) {
          acc[i][j] = __builtin_amdgcn_mfma_f32_16x16x32_bf16(al[i], bh[j], acc[i][j], 0, 0, 0);
          acc[i][j] = __builtin_amdgcn_mfma_f32_16x16x32_bf16(ah[i], bl[j], acc[i][j], 0, 0, 0);
          acc[i][j] = __builtin_amdgcn_mfma_f32_16x16x32_bf16(ah[i], bh[j], acc[i][j], 0, 0, 0);
        }
    }
    __syncthreads();
  }
  // epilogue: reference fp32 chain, dist store, per-(row,64tile) packed min
  const int n0 = (ntile << 7) + (wr << 6);
  const int k0 = (ktile << 7) + (wc << 6);
  const int g = lane >> 4, tl = lane & 15;
  const int tileidx = (ktile << 1) + wc;
  float en[4];
#pragma unroll
  for (int j = 0; j < 4; ++j) en[j] = embnorm[k0 + (j << 4) + tl];
#pragma unroll
  for (int i = 0; i < 4; ++i) {
#pragma unroll
    for (int r = 0; r < 4; ++r) {
      const int n = n0 + (i << 4) + (g << 2) + r;
      const float rn = rownorm[n];
      float* drow = dist + (size_t)n * 1024 + k0 + tl;
      unsigned long long key = ~0ULL;
#pragma unroll
      for (int j = 0; j < 4; ++j) {
        const float dv = __fsub_rn(__fadd_rn(rn, en[j]), __fmul_rn(2.0f, acc[i][j][r]));
        drow[j << 4] = dv;
        const unsigned long long c =
            ((unsigned long long)enc_f(dv) << 32) | (unsigned)(k0 + (j << 4) + tl);
        key = c < key ? c : key;
      }
#pragma unroll
      for (int mm = 1; mm < 16; mm <<= 1) {
        const unsigned long long o = __shfl_xor(key, mm, 64);
        key = o < key ? o : key;
      }
      if (tl == 0) pkey[(size_t)n * 16 + tileidx] = key;
    }
  }
}

// One wave per row: merge 16 partials, rescan qualifying 64-tiles, exact fp64-dot
// re-evaluation of candidates within window; first-index tie-break. Also emits
// index output + histogram.
__launch_bounds__(256)
__global__ void refine_kernel(const float* __restrict__ z_e,
                              const float* __restrict__ emb,
                              const float* __restrict__ rownorm,
                              const float* __restrict__ embnorm,
                              const float* __restrict__ dist,
                              const unsigned long long* __restrict__ pkey,
                              int* __restrict__ idx_ws,
                              float* __restrict__ out,
                              float* __restrict__ counts) {
  __shared__ float xl[16][260];
  const int t = threadIdx.x;
  const int s0 = blockIdx.x << 4;
  const int b = s0 >> 10, sb = s0 & 1023;
  {
    const int d = t >> 2;
    const int s4 = (t & 3) << 2;
#pragma unroll
    for (int p = 0; p < 4; ++p) {
      const int dd = d + p * 64;
      const float4 v = *(const float4*)(z_e + ((size_t)b << 18) + ((size_t)dd << 10) + sb + s4);
      xl[s4 + 0][dd] = v.x; xl[s4 + 1][dd] = v.y;
      xl[s4 + 2][dd] = v.z; xl[s4 + 3][dd] = v.w;
    }
  }
  __syncthreads();
  const int wv = t >> 6, lane = t & 63;
  for (int rr = 0; rr < 4; ++rr) {
    const int srow = (wv << 2) + rr;
    const int n = s0 + srow;
    const unsigned long long mypk = (lane < 16) ? pkey[(size_t)n * 16 + lane] : ~0ULL;
    unsigned long long key = mypk;
#pragma unroll
    for (int mm = 1; mm < 64; mm <<= 1) {
      const unsigned long long o = __shfl_xor(key, mm, 64);
      key = o < key ? o : key;
    }
    const float v1 = dec_f((unsigned)(key >> 32));
    const unsigned ue = (__float_as_uint(v1) >> 23) & 0xffu;
    const float ulp = __uint_as_float((ue - 23) << 23);
    const float w = v1 + 2.0f * ulp + 8e-6f;
    unsigned qmask = (unsigned)(__ballot(dec_f((unsigned)(mypk >> 32)) <= w) & 0xffffULL);
    const float rn = rownorm[n];
    const float4 xv = *(const float4*)(&xl[srow][lane << 2]);
    unsigned long long best = ~0ULL;
    while (qmask) {
      const int T = __ffs(qmask) - 1;
      qmask &= qmask - 1;
      const float dval = dist[(size_t)n * 1024 + T * 64 + lane];
      unsigned long long cm = __ballot(dval <= w);
      while (cm) {
        const int l2 = __ffsll(cm) - 1;
        cm &= cm - 1;
        const int kk = T * 64 + l2;
        const float4 ev = *(const float4*)(emb + ((size_t)kk << 8) + (lane << 2));
        double p = (double)xv.x * ev.x + (double)xv.y * ev.y
                 + (double)xv.z * ev.z + (double)xv.w * ev.w;
#pragma unroll
        for (int mm = 1; mm < 64; mm <<= 1) p += __shfl_xor(p, mm, 64);
        const float dotf = (float)p;
        const float D = __fsub_rn(__fadd_rn(rn, embnorm[kk]), __fmul_rn(2.0f, dotf));
        const unsigned long long c = ((unsigned long long)enc_f(D) << 32) | (unsigned)kk;
        best = c < best ? c : best;
      }
    }
    const int bestk = (int)(best & 0xffffffffu);
    if (lane == 0) {
      idx_ws[n] = bestk;
      out[IDX_OFF + n] = (float)bestk;
      atomicAdd(&counts[bestk], 1.0f);
    }
  }
}

// Coalesced straight-through + loss: block = 128 rows x 256 d; wave owns a 64-d
// quarter; lane owns 2 consecutive s. emb gather is float4 row-sequential per lane
// (full cache-line consumption over 4 consecutive d-iterations).
__launch_bounds__(256)
__global__ void zqloss_kernel(const float* __restrict__ z_e, const float* __restrict__ emb,
                              const int* __restrict__ idx_ws, float* __restrict__ out,
                              float* __restrict__ lossacc) {
  const int t = threadIdx.x;
  const int wv = t >> 6, lane = t & 63;
  const int n0 = blockIdx.x << 7;
  const int b = n0 >> 10, sb = n0 & 1023;
  const int s2 = lane << 1;
  const int2 ii = *(const int2*)(idx_ws + n0 + s2);
  const float* e0 = emb + ((size_t)ii.x << 8);
  const float* e1 = emb + ((size_t)ii.y << 8);
  const size_t zb = ((size_t)b << 18) + (size_t)(sb + s2);
  float lsum = 0.f;
#pragma unroll 2
  for (int u = 0; u < 16; ++u) {
    const int d = (wv << 6) + (u << 2);
    const float4 ev0 = *(const float4*)(e0 + d);
    const float4 ev1 = *(const float4*)(e1 + d);
    const float q0[4] = {ev0.x, ev0.y, ev0.z, ev0.w};
    const float q1[4] = {ev1.x, ev1.y, ev1.z, ev1.w};
#pragma unroll
    for (int j = 0; j < 4; ++j) {
      const size_t off = zb + ((size_t)(d + j) << 10);
      const float2 z = *(const float2*)(z_e + off);
      const float df0 = __fsub_rn(q0[j], z.x);
      const float df1 = __fsub_rn(q1[j], z.y);
      float2 ov;
      ov.x = __fadd_rn(z.x, df0);          // z + (z_q - z)
      ov.y = __fadd_rn(z.y, df1);
      *(float2*)(out + ZQ_OFF + off) = ov;
      lsum = fmaf(df0, df0, lsum);
      lsum = fmaf(df1, df1, lsum);
    }
  }
#pragma unroll
  for (int m = 32; m > 0; m >>= 1) lsum += __shfl_xor(lsum, m, 64);
  __shared__ float wred[4];
  if ((t & 63) == 0) wred[t >> 6] = lsum;
  __syncthreads();
  if (t == 0) atomicAdd(lossacc, wred[0] + wred[1] + wred[2] + wred[3]);
}

__launch_bounds__(256)
__global__ void final_kernel(const float* __restrict__ counts, const float* __restrict__ lossacc,
                             float* __restrict__ out) {
  const int t = threadIdx.x;
  float ssum = 0.f;
#pragma unroll
  for (int u = 0; u < 4; ++u) {
    const float p = counts[t * 4 + u] * (1.0f / 32768.0f);
    ssum += p * logf(p + 1e-10f);
  }
#pragma unroll
  for (int m = 32; m > 0; m >>= 1) ssum += __shfl_xor(ssum, m, 64);
  __shared__ float wred[4];
  if ((t & 63) == 0) wred[t >> 6] = ssum;
  __syncthreads();
  if (t == 0) {
    const float tot = wred[0] + wred[1] + wred[2] + wred[3];
    out[PERP_OFF] = expf(-tot);
    const float mql = lossacc[0] * (1.0f / 8388608.0f);
    out[LOSS_OFF] = __fadd_rn(mql, __fmul_rn(0.25f, mql));
  }
}

extern "C" void kernel_launch(void* const* d_in, const int* in_sizes, int n_in,
                              void* d_out, int out_size, void* d_ws, size_t ws_size,
                              hipStream_t stream) {
  const float* z_e = (const float*)d_in[0];
  const float* emb = (const float*)d_in[1];
  float* out = (float*)d_out;
  char* ws = (char*)d_ws;

  unsigned short* ahi = (unsigned short*)(ws + WSB_AHI);
  unsigned short* alo = (unsigned short*)(ws + WSB_ALO);
  unsigned short* bhi = (unsigned short*)(ws + WSB_BHI);
  unsigned short* blo = (unsigned short*)(ws + WSB_BLO);
  float* rownorm = (float*)(ws + WSB_RN);
  float* embnorm = (float*)(ws + WSB_EN);
  unsigned long long* pkey = (unsigned long long*)(ws + WSB_PKEY);
  int* idx_ws = (int*)(ws + WSB_IDX);
  float* counts = (float*)(ws + WSB_CNT);
  float* lossacc = (float*)(ws + WSB_LOSS);

  hipMemsetAsync(ws + WSB_CNT, 0, 4100, stream);

  hipLaunchKernelGGL(embnorm_kernel, dim3(4), dim3(256), 0, stream, emb, embnorm);
  hipLaunchKernelGGL(rownorm_kernel, dim3(128), dim3(256), 0, stream, z_e, rownorm);
  hipLaunchKernelGGL(prepA_kernel, dim3(2048), dim3(256), 0, stream, z_e, ahi, alo);
  hipLaunchKernelGGL(prepB_kernel, dim3(128), dim3(256), 0, stream, emb, bhi, blo);
  hipLaunchKernelGGL(dist_kernel, dim3(2048), dim3(256), 0, stream,
                     ahi, alo, bhi, blo, rownorm, embnorm, out + DIST_OFF, pkey);
  hipLaunchKernelGGL(refine_kernel, dim3(2048), dim3(256), 0, stream,
                     z_e, emb, rownorm, embnorm, out + DIST_OFF, pkey, idx_ws, out, counts);
  hipLaunchKernelGGL(zqloss_kernel, dim3(256), dim3(256), 0, stream,
                     z_e, emb, idx_ws, out, lossacc);
  hipLaunchKernelGGL(final_kernel, dim3(1), dim3(256), 0, stream, counts, lossacc, out);
}

// Round 5
// 166.422 us; speedup vs baseline: 3.2732x; 1.1308x over previous
//
#include <hip/hip_runtime.h>
#include <cfloat>

typedef __attribute__((ext_vector_type(8))) short bf16x8;
typedef __attribute__((ext_vector_type(4))) float f32x4;
typedef __attribute__((ext_vector_type(8))) unsigned short u16x8;

#define NROW 32768
#define ZQ_OFF   0
#define LOSS_OFF 8388608
#define PERP_OFF 8388609
#define IDX_OFF  8388610
#define DIST_OFF 8421378

// ws byte offsets
#define WSB_AHI  0x0
#define WSB_ALO  0x1000000
#define WSB_BHI  0x2000000
#define WSB_BLO  0x2080000
#define WSB_RN   0x2100000
#define WSB_EN   0x2120000
#define WSB_PKEY 0x2200000
#define WSB_CNT  0x2620000
#define WSB_LOSS 0x2621000

__device__ __forceinline__ float sq_rn(float x) { return __fmul_rn(x, x); }

__device__ __forceinline__ unsigned enc_f(float f) {
  unsigned u = __float_as_uint(f);
  return (u & 0x80000000u) ? ~u : (u | 0x80000000u);
}
__device__ __forceinline__ float dec_f(unsigned e) {
  unsigned u = (e & 0x80000000u) ? (e ^ 0x80000000u) : ~e;
  return __uint_as_float(u);
}

__device__ __forceinline__ unsigned short bf16_rne(float f) {
  unsigned u = __float_as_uint(f);
  unsigned r = u + 0x7fffu + ((u >> 16) & 1u);
  return (unsigned short)(r >> 16);
}

__device__ __forceinline__ void gload16(const void* g, void* l) {
  __builtin_amdgcn_global_load_lds(
      (const __attribute__((address_space(1))) unsigned int*)g,
      (__attribute__((address_space(3))) unsigned int*)l, 16, 0, 0);
}

// numpy pairwise_sum order for 256-length sum of squares (load-bearing: feeds the
// big part of the distance chain; must match np bit-exactly).
__device__ float pairwise_norm256(const float* __restrict__ p, int stride) {
  float h[2];
#pragma unroll
  for (int half = 0; half < 2; ++half) {
    const float* q = p + (size_t)half * 128 * stride;
    float r[8];
#pragma unroll
    for (int j = 0; j < 8; ++j) r[j] = sq_rn(q[(size_t)j * stride]);
    for (int d8 = 8; d8 < 128; d8 += 8) {
#pragma unroll
      for (int j = 0; j < 8; ++j)
        r[j] = __fadd_rn(r[j], sq_rn(q[(size_t)(d8 + j) * stride]));
    }
    h[half] = __fadd_rn(__fadd_rn(__fadd_rn(r[0], r[1]), __fadd_rn(r[2], r[3])),
                        __fadd_rn(__fadd_rn(r[4], r[5]), __fadd_rn(r[6], r[7])));
  }
  return __fadd_rn(h[0], h[1]);
}

__launch_bounds__(256)
__global__ void embnorm_kernel(const float* __restrict__ emb, float* __restrict__ embnorm) {
  const int k = blockIdx.x * 256 + threadIdx.x;
  embnorm[k] = pairwise_norm256(emb + ((size_t)k << 8), 1);
}

// Fused rownorm + A-plane prep. One block per 128-row ntile; reads z_e once.
// Norm accumulation replicates numpy pairwise order exactly: per 128-half, 8
// accumulators r[j] over sequential d (chunks processed in increasing d continue
// the same sequential order), tree-combined as in pairwise_norm256.
__launch_bounds__(256)
__global__ void prep_kernel(const float* __restrict__ z_e,
                            unsigned short* __restrict__ ahi,
                            unsigned short* __restrict__ alo,
                            float* __restrict__ rownorm) {
  __shared__ float xt[64][132];
  __shared__ float hs[128][2];
  const int t = threadIdx.x;
  const int ntile = blockIdx.x;
  const int n0 = ntile << 7;
  const int b = n0 >> 10, s0 = n0 & 1023;
  const size_t zb = ((size_t)b << 18) + (size_t)s0;
  const int myhalf = t >> 7;
  const int mys = t & 127;
  float r[8];
#pragma unroll
  for (int j = 0; j < 8; ++j) r[j] = 0.f;   // +0 + x*x is bit-exact (squares >= 0)
  for (int dt = 0; dt < 4; ++dt) {
    // stage 64 d x 128 s (fp32, XOR-swizzled columns)
#pragma unroll
    for (int p = 0; p < 8; ++p) {
      const int idx = (p << 8) + t;
      const int dd = idx >> 5;
      const int sq = (idx & 31) << 2;
      const float4 v = *(const float4*)(z_e + zb + ((size_t)((dt << 6) + dd) << 10) + sq);
      const int sw = ((dd >> 3) & 3) << 3;
      *(float4*)(&xt[dd][sq ^ sw]) = v;
    }
    __syncthreads();
    // norm partial, by the half that owns this dt (dt 0,1 -> half 0; 2,3 -> half 1)
    if ((dt >> 1) == myhalf) {
#pragma unroll
      for (int g = 0; g < 8; ++g) {
        const int col = mys ^ ((g & 3) << 3);
#pragma unroll
        for (int j = 0; j < 8; ++j)
          r[j] = __fadd_rn(r[j], sq_rn(xt[(g << 3) + j][col]));
      }
    }
    // bf16 hi/lo emit (same global layout as before)
#pragma unroll
    for (int p = 0; p < 4; ++p) {
      const int idx = (p << 8) + t;
      const int s = idx >> 3, c = idx & 7;
      const int sw = (c & 3) << 3;
      u16x8 vh, vl;
#pragma unroll
      for (int u = 0; u < 8; ++u) {
        const float x = xt[(c << 3) + u][s ^ sw];
        const unsigned short h = bf16_rne(x);
        vh[u] = (short)h;
        vl[u] = (short)bf16_rne(x - __uint_as_float((unsigned)h << 16));
      }
      const size_t pos = ((size_t)ntile << 12) + ((size_t)dt << 10)
                       + (size_t)(s << 3) + (size_t)(c ^ (s & 7));
      *(u16x8*)(ahi + pos * 8) = vh;
      *(u16x8*)(alo + pos * 8) = vl;
    }
    __syncthreads();
  }
  const float h = __fadd_rn(__fadd_rn(__fadd_rn(r[0], r[1]), __fadd_rn(r[2], r[3])),
                            __fadd_rn(__fadd_rn(r[4], r[5]), __fadd_rn(r[6], r[7])));
  hs[mys][myhalf] = h;
  __syncthreads();
  if (t < 128) rownorm[n0 + t] = __fadd_rn(hs[t][0], hs[t][1]);
}

__launch_bounds__(256)
__global__ void prepB_kernel(const float* __restrict__ emb,
                             unsigned short* __restrict__ bhi,
                             unsigned short* __restrict__ blo) {
  const int tg = blockIdx.x * 256 + threadIdx.x;   // 32768
  const int k = tg >> 5, cd = tg & 31;
  const float4 v0 = *(const float4*)(emb + ((size_t)k << 8) + cd * 8);
  const float4 v1 = *(const float4*)(emb + ((size_t)k << 8) + cd * 8 + 4);
  const float xs[8] = {v0.x, v0.y, v0.z, v0.w, v1.x, v1.y, v1.z, v1.w};
  u16x8 vh, vl;
#pragma unroll
  for (int u = 0; u < 8; ++u) {
    const unsigned short h = bf16_rne(xs[u]);
    vh[u] = (short)h;
    vl[u] = (short)bf16_rne(xs[u] - __uint_as_float((unsigned)h << 16));
  }
  const size_t pos = (((size_t)(k >> 7)) << 12) + ((size_t)(cd >> 3) << 10)
                   + ((size_t)(k & 127) << 3) + (size_t)((cd & 7) ^ (k & 7));
  *(u16x8*)(bhi + pos * 8) = vh;
  *(u16x8*)(blo + pos * 8) = vl;
}

#define LDS_AHI 0
#define LDS_ALO 16384
#define LDS_BHI 32768
#define LDS_BLO 49152

// 128x128 tile, 4 waves of 64x64, bf16x3 MFMA. Writes dist + per-(row,64tile) pkey.
// Flattened grid (2048) with XCD-chunked mapping: each XCD runs 32 ntiles with all
// 8 ktiles back-to-back so the A-tile is L2-resident for 7 of its 8 uses.
__launch_bounds__(256, 2)
__global__ void dist_kernel(const unsigned short* __restrict__ ahi,
                            const unsigned short* __restrict__ alo,
                            const unsigned short* __restrict__ bhi,
                            const unsigned short* __restrict__ blo,
                            const float* __restrict__ rownorm,
                            const float* __restrict__ embnorm,
                            float* __restrict__ dist,
                            unsigned long long* __restrict__ pkey) {
  __shared__ char lds[65536];
  const int tid = threadIdx.x;
  const int lane = tid & 63;
  const int wv = tid >> 6;
  const int wr = wv >> 1, wc = wv & 1;
  const int bid = blockIdx.x;
  const int xcd = bid & 7;
  const int jj = bid >> 3;
  const int ntile = (xcd << 5) + (jj >> 3);
  const int ktile = jj & 7;

  const unsigned short* gsrc =
      (wv == 0) ? ahi + ((size_t)ntile << 15) :
      (wv == 1) ? alo + ((size_t)ntile << 15) :
      (wv == 2) ? bhi + ((size_t)ktile << 15) :
                  blo + ((size_t)ktile << 15);
  char* ldsArr = lds + (wv << 14);

  f32x4 acc[4][4];
#pragma unroll
  for (int i = 0; i < 4; ++i)
#pragma unroll
    for (int j = 0; j < 4; ++j) acc[i][j] = (f32x4){0.f, 0.f, 0.f, 0.f};

  for (int s = 0; s < 4; ++s) {
    {
      const unsigned short* g = gsrc + ((size_t)s << 13);
#pragma unroll
      for (int q = 0; q < 16; ++q)
        gload16(g + (((size_t)(q * 64 + lane)) << 3), ldsArr + q * 1024);
    }
    __syncthreads();
#pragma unroll
    for (int half = 0; half < 2; ++half) {
      const int kb = half << 2;
      bf16x8 ah[4], al[4], bh[4], bl[4];
#pragma unroll
      for (int i = 0; i < 4; ++i) {
        const int row = (wr << 6) + (i << 4) + (lane & 15);
        const int ch = (kb + (lane >> 4)) ^ (row & 7);
        ah[i] = *(const bf16x8*)(lds + LDS_AHI + ((row << 3) + ch) * 16);
        al[i] = *(const bf16x8*)(lds + LDS_ALO + ((row << 3) + ch) * 16);
      }
#pragma unroll
      for (int j = 0; j < 4; ++j) {
        const int row = (wc << 6) + (j << 4) + (lane & 15);
        const int ch = (kb + (lane >> 4)) ^ (row & 7);
        bh[j] = *(const bf16x8*)(lds + LDS_BHI + ((row << 3) + ch) * 16);
        bl[j] = *(const bf16x8*)(lds + LDS_BLO + ((row << 3) + ch) * 16);
      }
#pragma unroll
      for (int i = 0; i < 4; ++i)
#pragma unroll
        for (int j = 0; j < 4; ++j) {
          acc[i][j] = __builtin_amdgcn_mfma_f32_16x16x32_bf16(al[i], bh[j], acc[i][j], 0, 0, 0);
          acc[i][j] = __builtin_amdgcn_mfma_f32_16x16x32_bf16(ah[i], bl[j], acc[i][j], 0, 0, 0);
          acc[i][j] = __builtin_amdgcn_mfma_f32_16x16x32_bf16(ah[i], bh[j], acc[i][j], 0, 0, 0);
        }
    }
    __syncthreads();
  }
  // epilogue: reference fp32 chain, dist store, per-(row,64tile) packed min
  const int n0 = (ntile << 7) + (wr << 6);
  const int k0 = (ktile << 7) + (wc << 6);
  const int g = lane >> 4, tl = lane & 15;
  const int tileidx = (ktile << 1) + wc;
  float en[4];
#pragma unroll
  for (int j = 0; j < 4; ++j) en[j] = embnorm[k0 + (j << 4) + tl];
#pragma unroll
  for (int i = 0; i < 4; ++i) {
#pragma unroll
    for (int r = 0; r < 4; ++r) {
      const int n = n0 + (i << 4) + (g << 2) + r;
      const float rn = rownorm[n];
      float* drow = dist + (size_t)n * 1024 + k0 + tl;
      unsigned long long key = ~0ULL;
#pragma unroll
      for (int j = 0; j < 4; ++j) {
        const float dv = __fsub_rn(__fadd_rn(rn, en[j]), __fmul_rn(2.0f, acc[i][j][r]));
        drow[j << 4] = dv;
        const unsigned long long c =
            ((unsigned long long)enc_f(dv) << 32) | (unsigned)(k0 + (j << 4) + tl);
        key = c < key ? c : key;
      }
#pragma unroll
      for (int mm = 1; mm < 16; mm <<= 1) {
        const unsigned long long o = __shfl_xor(key, mm, 64);
        key = o < key ? o : key;
      }
      if (tl == 0) pkey[(size_t)n * 16 + tileidx] = key;
    }
  }
}

// Fused refine + straight-through + loss + histogram + index output.
// Refine semantics identical to previous rounds (exact fp64-dot re-eval of window
// candidates, first-index tie-break). Then the same block computes z_q for its 16
// rows from the staged z_e and writes coalesced 64B lines per (d, 16-s) chunk.
__launch_bounds__(256)
__global__ void rzq_kernel(const float* __restrict__ z_e,
                           const float* __restrict__ emb,
                           const float* __restrict__ rownorm,
                           const float* __restrict__ embnorm,
                           const float* __restrict__ dist,
                           const unsigned long long* __restrict__ pkey,
                           float* __restrict__ out,
                           float* __restrict__ counts,
                           float* __restrict__ lossacc) {
  __shared__ float xl[16][260];
  __shared__ int bk_s[16];
  __shared__ float wredf[4];
  const int t = threadIdx.x;
  const int s0 = blockIdx.x << 4;
  const int b = s0 >> 10, sb = s0 & 1023;
  {
    const int d = t >> 2;
    const int s4 = (t & 3) << 2;
#pragma unroll
    for (int p = 0; p < 4; ++p) {
      const int dd = d + p * 64;
      const float4 v = *(const float4*)(z_e + ((size_t)b << 18) + ((size_t)dd << 10) + sb + s4);
      xl[s4 + 0][dd] = v.x; xl[s4 + 1][dd] = v.y;
      xl[s4 + 2][dd] = v.z; xl[s4 + 3][dd] = v.w;
    }
  }
  __syncthreads();
  const int wv = t >> 6, lane = t & 63;
  for (int rr = 0; rr < 4; ++rr) {
    const int srow = (wv << 2) + rr;
    const int n = s0 + srow;
    const unsigned long long mypk = (lane < 16) ? pkey[(size_t)n * 16 + lane] : ~0ULL;
    unsigned long long key = mypk;
#pragma unroll
    for (int mm = 1; mm < 64; mm <<= 1) {
      const unsigned long long o = __shfl_xor(key, mm, 64);
      key = o < key ? o : key;
    }
    const float v1 = dec_f((unsigned)(key >> 32));
    const unsigned ue = (__float_as_uint(v1) >> 23) & 0xffu;
    const float ulp = __uint_as_float((ue - 23) << 23);
    const float w = v1 + 2.0f * ulp + 8e-6f;
    unsigned qmask = (unsigned)(__ballot(dec_f((unsigned)(mypk >> 32)) <= w) & 0xffffULL);
    const float rn = rownorm[n];
    const float4 xv = *(const float4*)(&xl[srow][lane << 2]);
    unsigned long long best = ~0ULL;
    while (qmask) {
      const int T = __ffs(qmask) - 1;
      qmask &= qmask - 1;
      const float dval = dist[(size_t)n * 1024 + T * 64 + lane];
      unsigned long long cm = __ballot(dval <= w);
      while (cm) {
        const int l2 = __ffsll(cm) - 1;
        cm &= cm - 1;
        const int kk = T * 64 + l2;
        const float4 ev = *(const float4*)(emb + ((size_t)kk << 8) + (lane << 2));
        double p = (double)xv.x * ev.x + (double)xv.y * ev.y
                 + (double)xv.z * ev.z + (double)xv.w * ev.w;
#pragma unroll
        for (int mm = 1; mm < 64; mm <<= 1) p += __shfl_xor(p, mm, 64);
        const float dotf = (float)p;
        const float D = __fsub_rn(__fadd_rn(rn, embnorm[kk]), __fmul_rn(2.0f, dotf));
        const unsigned long long c = ((unsigned long long)enc_f(D) << 32) | (unsigned)kk;
        best = c < best ? c : best;
      }
    }
    const int bestk = (int)(best & 0xffffffffu);
    if (lane == 0) {
      bk_s[srow] = bestk;
      out[IDX_OFF + n] = (float)bestk;
      atomicAdd(&counts[bestk], 1.0f);
    }
  }
  __syncthreads();
  // z_q + loss phase: thread t owns dim d=t for all 16 rows
  const int d = t;
  float zq[16];
  float lsum = 0.f;
#pragma unroll
  for (int r2 = 0; r2 < 16; ++r2) {
    const float e = emb[((size_t)bk_s[r2] << 8) + d];
    const float z = xl[r2][d];
    const float df = __fsub_rn(e, z);
    zq[r2] = __fadd_rn(z, df);            // z + (z_q - z)
    lsum = fmaf(df, df, lsum);
  }
  float* op = out + ZQ_OFF + ((size_t)b << 18) + ((size_t)d << 10) + sb;
#pragma unroll
  for (int q = 0; q < 4; ++q)
    *(float4*)(op + (q << 2)) =
        make_float4(zq[q * 4], zq[q * 4 + 1], zq[q * 4 + 2], zq[q * 4 + 3]);
#pragma unroll
  for (int m = 32; m > 0; m >>= 1) lsum += __shfl_xor(lsum, m, 64);
  if (lane == 0) wredf[wv] = lsum;
  __syncthreads();
  if (t == 0) atomicAdd(lossacc, wredf[0] + wredf[1] + wredf[2] + wredf[3]);
}

__launch_bounds__(256)
__global__ void final_kernel(const float* __restrict__ counts, const float* __restrict__ lossacc,
                             float* __restrict__ out) {
  const int t = threadIdx.x;
  float ssum = 0.f;
#pragma unroll
  for (int u = 0; u < 4; ++u) {
    const float p = counts[t * 4 + u] * (1.0f / 32768.0f);
    ssum += p * logf(p + 1e-10f);
  }
#pragma unroll
  for (int m = 32; m > 0; m >>= 1) ssum += __shfl_xor(ssum, m, 64);
  __shared__ float wred[4];
  if ((t & 63) == 0) wred[t >> 6] = ssum;
  __syncthreads();
  if (t == 0) {
    const float tot = wred[0] + wred[1] + wred[2] + wred[3];
    out[PERP_OFF] = expf(-tot);
    const float mql = lossacc[0] * (1.0f / 8388608.0f);
    out[LOSS_OFF] = __fadd_rn(mql, __fmul_rn(0.25f, mql));
  }
}

extern "C" void kernel_launch(void* const* d_in, const int* in_sizes, int n_in,
                              void* d_out, int out_size, void* d_ws, size_t ws_size,
                              hipStream_t stream) {
  const float* z_e = (const float*)d_in[0];
  const float* emb = (const float*)d_in[1];
  float* out = (float*)d_out;
  char* ws = (char*)d_ws;

  unsigned short* ahi = (unsigned short*)(ws + WSB_AHI);
  unsigned short* alo = (unsigned short*)(ws + WSB_ALO);
  unsigned short* bhi = (unsigned short*)(ws + WSB_BHI);
  unsigned short* blo = (unsigned short*)(ws + WSB_BLO);
  float* rownorm = (float*)(ws + WSB_RN);
  float* embnorm = (float*)(ws + WSB_EN);
  unsigned long long* pkey = (unsigned long long*)(ws + WSB_PKEY);
  float* counts = (float*)(ws + WSB_CNT);
  float* lossacc = (float*)(ws + WSB_LOSS);

  hipMemsetAsync(ws + WSB_CNT, 0, 4100, stream);

  hipLaunchKernelGGL(embnorm_kernel, dim3(4), dim3(256), 0, stream, emb, embnorm);
  hipLaunchKernelGGL(prepB_kernel, dim3(128), dim3(256), 0, stream, emb, bhi, blo);
  hipLaunchKernelGGL(prep_kernel, dim3(256), dim3(256), 0, stream, z_e, ahi, alo, rownorm);
  hipLaunchKernelGGL(dist_kernel, dim3(2048), dim3(256), 0, stream,
                     ahi, alo, bhi, blo, rownorm, embnorm, out + DIST_OFF, pkey);
  hipLaunchKernelGGL(rzq_kernel, dim3(2048), dim3(256), 0, stream,
                     z_e, emb, rownorm, embnorm, out + DIST_OFF, pkey, out, counts, lossacc);
  hipLaunchKernelGGL(final_kernel, dim3(1), dim3(256), 0, stream, counts, lossacc, out);
}

// Round 6
// 132.520 us; speedup vs baseline: 4.1106x; 1.2558x over previous
//
#include <hip/hip_runtime.h>
#include <cfloat>

typedef __attribute__((ext_vector_type(8))) short bf16x8;
typedef __attribute__((ext_vector_type(4))) float f32x4;
typedef __attribute__((ext_vector_type(8))) unsigned short u16x8;

#define NROW 32768
#define ZQ_OFF   0
#define LOSS_OFF 8388608
#define PERP_OFF 8388609
#define IDX_OFF  8388610
#define DIST_OFF 8421378

// ws byte offsets
#define WSB_AHI  0x0
#define WSB_BHI  0x1000000
#define WSB_RN   0x2100000
#define WSB_EN   0x2120000
#define WSB_PKEY 0x2200000
#define WSB_CNT  0x2620000
#define WSB_LOSS 0x2621000

__device__ __forceinline__ float sq_rn(float x) { return __fmul_rn(x, x); }

__device__ __forceinline__ unsigned enc_f(float f) {
  unsigned u = __float_as_uint(f);
  return (u & 0x80000000u) ? ~u : (u | 0x80000000u);
}
__device__ __forceinline__ float dec_f(unsigned e) {
  unsigned u = (e & 0x80000000u) ? (e ^ 0x80000000u) : ~e;
  return __uint_as_float(u);
}

__device__ __forceinline__ unsigned short bf16_rne(float f) {
  unsigned u = __float_as_uint(f);
  unsigned r = u + 0x7fffu + ((u >> 16) & 1u);
  return (unsigned short)(r >> 16);
}

__device__ __forceinline__ void gload16(const void* g, void* l) {
  __builtin_amdgcn_global_load_lds(
      (const __attribute__((address_space(1))) unsigned int*)g,
      (__attribute__((address_space(3))) unsigned int*)l, 16, 0, 0);
}

// numpy pairwise_sum order for 256-length sum of squares (load-bearing: feeds the
// big part of the distance chain; must match np bit-exactly).
__device__ float pairwise_norm256(const float* __restrict__ p, int stride) {
  float h[2];
#pragma unroll
  for (int half = 0; half < 2; ++half) {
    const float* q = p + (size_t)half * 128 * stride;
    float r[8];
#pragma unroll
    for (int j = 0; j < 8; ++j) r[j] = sq_rn(q[(size_t)j * stride]);
    for (int d8 = 8; d8 < 128; d8 += 8) {
#pragma unroll
      for (int j = 0; j < 8; ++j)
        r[j] = __fadd_rn(r[j], sq_rn(q[(size_t)(d8 + j) * stride]));
    }
    h[half] = __fadd_rn(__fadd_rn(__fadd_rn(r[0], r[1]), __fadd_rn(r[2], r[3])),
                        __fadd_rn(__fadd_rn(r[4], r[5]), __fadd_rn(r[6], r[7])));
  }
  return __fadd_rn(h[0], h[1]);
}

// Fused B-plane prep + embnorm (both read emb; blocks 0..127 emit bhi,
// blocks 128..131 emit embnorm).
__launch_bounds__(256)
__global__ void prepE_kernel(const float* __restrict__ emb,
                             unsigned short* __restrict__ bhi,
                             float* __restrict__ embnorm) {
  if (blockIdx.x >= 128) {
    const int k = ((blockIdx.x - 128) << 8) + threadIdx.x;
    embnorm[k] = pairwise_norm256(emb + ((size_t)k << 8), 1);
    return;
  }
  const int tg = (blockIdx.x << 8) + threadIdx.x;   // 32768
  const int k = tg >> 5, cd = tg & 31;
  const float4 v0 = *(const float4*)(emb + ((size_t)k << 8) + cd * 8);
  const float4 v1 = *(const float4*)(emb + ((size_t)k << 8) + cd * 8 + 4);
  const float xs[8] = {v0.x, v0.y, v0.z, v0.w, v1.x, v1.y, v1.z, v1.w};
  u16x8 vh;
#pragma unroll
  for (int u = 0; u < 8; ++u) vh[u] = (short)bf16_rne(xs[u]);
  const size_t pos = (((size_t)(k >> 7)) << 12) + ((size_t)(cd >> 3) << 10)
                   + ((size_t)(k & 127) << 3) + (size_t)((cd & 7) ^ (k & 7));
  *(u16x8*)(bhi + pos * 8) = vh;
}

// Fused rownorm + A-plane prep. One block per 128-row ntile; reads z_e once.
// Norm accumulation replicates numpy pairwise order exactly.
__launch_bounds__(256)
__global__ void prep_kernel(const float* __restrict__ z_e,
                            unsigned short* __restrict__ ahi,
                            float* __restrict__ rownorm) {
  __shared__ float xt[64][132];
  __shared__ float hs[128][2];
  const int t = threadIdx.x;
  const int ntile = blockIdx.x;
  const int n0 = ntile << 7;
  const int b = n0 >> 10, s0 = n0 & 1023;
  const size_t zb = ((size_t)b << 18) + (size_t)s0;
  const int myhalf = t >> 7;
  const int mys = t & 127;
  float r[8];
#pragma unroll
  for (int j = 0; j < 8; ++j) r[j] = 0.f;   // +0 + x*x is bit-exact (squares >= 0)
  for (int dt = 0; dt < 4; ++dt) {
    // stage 64 d x 128 s (fp32, XOR-swizzled columns)
#pragma unroll
    for (int p = 0; p < 8; ++p) {
      const int idx = (p << 8) + t;
      const int dd = idx >> 5;
      const int sq = (idx & 31) << 2;
      const float4 v = *(const float4*)(z_e + zb + ((size_t)((dt << 6) + dd) << 10) + sq);
      const int sw = ((dd >> 3) & 3) << 3;
      *(float4*)(&xt[dd][sq ^ sw]) = v;
    }
    __syncthreads();
    // norm partial, by the half that owns this dt (dt 0,1 -> half 0; 2,3 -> half 1)
    if ((dt >> 1) == myhalf) {
#pragma unroll
      for (int g = 0; g < 8; ++g) {
        const int col = mys ^ ((g & 3) << 3);
#pragma unroll
        for (int j = 0; j < 8; ++j)
          r[j] = __fadd_rn(r[j], sq_rn(xt[(g << 3) + j][col]));
      }
    }
    // bf16 hi emit (same global layout/swizzle keying as before, hi plane only)
#pragma unroll
    for (int p = 0; p < 4; ++p) {
      const int idx = (p << 8) + t;
      const int s = idx >> 3, c = idx & 7;
      const int sw = (c & 3) << 3;
      u16x8 vh;
#pragma unroll
      for (int u = 0; u < 8; ++u)
        vh[u] = (short)bf16_rne(xt[(c << 3) + u][s ^ sw]);
      const size_t pos = ((size_t)ntile << 12) + ((size_t)dt << 10)
                       + (size_t)(s << 3) + (size_t)(c ^ (s & 7));
      *(u16x8*)(ahi + pos * 8) = vh;
    }
    __syncthreads();
  }
  const float h = __fadd_rn(__fadd_rn(__fadd_rn(r[0], r[1]), __fadd_rn(r[2], r[3])),
                            __fadd_rn(__fadd_rn(r[4], r[5]), __fadd_rn(r[6], r[7])));
  hs[mys][myhalf] = h;
  __syncthreads();
  if (t < 128) rownorm[n0 + t] = __fadd_rn(hs[t][0], hs[t][1]);
}

#define LDS_A 0
#define LDS_B 16384

// 128x128 tile, 4 waves of 64x64, single plain-bf16 MFMA per fragment pair
// (proposal accuracy eps <= ||x||*||e||*2^-8 ~ 1.2e-3; refine window 3e-3 covers).
// Writes dist + per-(row,64tile) pkey. XCD-chunked block mapping for A-tile L2 reuse.
__launch_bounds__(256, 4)
__global__ void dist_kernel(const unsigned short* __restrict__ ahi,
                            const unsigned short* __restrict__ bhi,
                            const float* __restrict__ rownorm,
                            const float* __restrict__ embnorm,
                            float* __restrict__ dist,
                            unsigned long long* __restrict__ pkey) {
  __shared__ char lds[32768];
  const int tid = threadIdx.x;
  const int lane = tid & 63;
  const int wv = tid >> 6;
  const int wr = wv >> 1, wc = wv & 1;
  const int bid = blockIdx.x;
  const int xcd = bid & 7;
  const int jj = bid >> 3;
  const int ntile = (xcd << 5) + (jj >> 3);
  const int ktile = jj & 7;

  const unsigned short* gsrc = (wv < 2) ? ahi + ((size_t)ntile << 15)
                                        : bhi + ((size_t)ktile << 15);
  char* ldsBase = lds + ((wv >> 1) << 14);

  f32x4 acc[4][4];
#pragma unroll
  for (int i = 0; i < 4; ++i)
#pragma unroll
    for (int j = 0; j < 4; ++j) acc[i][j] = (f32x4){0.f, 0.f, 0.f, 0.f};

  for (int s = 0; s < 4; ++s) {
    {
      const unsigned short* g = gsrc + ((size_t)s << 13);
#pragma unroll
      for (int q = 0; q < 8; ++q) {
        const int cq = ((wv & 1) << 3) + q;
        gload16(g + ((size_t)(cq * 64 + lane) << 3), ldsBase + cq * 1024);
      }
    }
    __syncthreads();
#pragma unroll
    for (int half = 0; half < 2; ++half) {
      const int kb = half << 2;
      bf16x8 ah[4], bh[4];
#pragma unroll
      for (int i = 0; i < 4; ++i) {
        const int row = (wr << 6) + (i << 4) + (lane & 15);
        const int ch = (kb + (lane >> 4)) ^ (row & 7);
        ah[i] = *(const bf16x8*)(lds + LDS_A + ((row << 3) + ch) * 16);
      }
#pragma unroll
      for (int j = 0; j < 4; ++j) {
        const int row = (wc << 6) + (j << 4) + (lane & 15);
        const int ch = (kb + (lane >> 4)) ^ (row & 7);
        bh[j] = *(const bf16x8*)(lds + LDS_B + ((row << 3) + ch) * 16);
      }
#pragma unroll
      for (int i = 0; i < 4; ++i)
#pragma unroll
        for (int j = 0; j < 4; ++j)
          acc[i][j] = __builtin_amdgcn_mfma_f32_16x16x32_bf16(ah[i], bh[j], acc[i][j], 0, 0, 0);
    }
    __syncthreads();
  }
  // epilogue: reference fp32 chain, dist store, per-(row,64tile) packed min
  const int n0 = (ntile << 7) + (wr << 6);
  const int k0 = (ktile << 7) + (wc << 6);
  const int g = lane >> 4, tl = lane & 15;
  const int tileidx = (ktile << 1) + wc;
  float en[4];
#pragma unroll
  for (int j = 0; j < 4; ++j) en[j] = embnorm[k0 + (j << 4) + tl];
#pragma unroll
  for (int i = 0; i < 4; ++i) {
#pragma unroll
    for (int r = 0; r < 4; ++r) {
      const int n = n0 + (i << 4) + (g << 2) + r;
      const float rn = rownorm[n];
      float* drow = dist + (size_t)n * 1024 + k0 + tl;
      unsigned long long key = ~0ULL;
#pragma unroll
      for (int j = 0; j < 4; ++j) {
        const float dv = __fsub_rn(__fadd_rn(rn, en[j]), __fmul_rn(2.0f, acc[i][j][r]));
        drow[j << 4] = dv;
        const unsigned long long c =
            ((unsigned long long)enc_f(dv) << 32) | (unsigned)(k0 + (j << 4) + tl);
        key = c < key ? c : key;
      }
#pragma unroll
      for (int mm = 1; mm < 16; mm <<= 1) {
        const unsigned long long o = __shfl_xor(key, mm, 64);
        key = o < key ? o : key;
      }
      if (tl == 0) pkey[(size_t)n * 16 + tileidx] = key;
    }
  }
}

// Fused refine + straight-through + loss + histogram + index output.
// Window widened to cover bf16-proposal error (2*eps + fp32 slop < 3e-3); the
// exact fp64-dot re-evaluation + (value, index) ordering is unchanged, so extra
// candidates cannot change the result.
__launch_bounds__(256)
__global__ void rzq_kernel(const float* __restrict__ z_e,
                           const float* __restrict__ emb,
                           const float* __restrict__ rownorm,
                           const float* __restrict__ embnorm,
                           const float* __restrict__ dist,
                           const unsigned long long* __restrict__ pkey,
                           float* __restrict__ out,
                           float* __restrict__ counts,
                           float* __restrict__ lossacc) {
  __shared__ float xl[16][260];
  __shared__ int bk_s[16];
  __shared__ float wredf[4];
  const int t = threadIdx.x;
  const int s0 = blockIdx.x << 4;
  const int b = s0 >> 10, sb = s0 & 1023;
  {
    const int d = t >> 2;
    const int s4 = (t & 3) << 2;
#pragma unroll
    for (int p = 0; p < 4; ++p) {
      const int dd = d + p * 64;
      const float4 v = *(const float4*)(z_e + ((size_t)b << 18) + ((size_t)dd << 10) + sb + s4);
      xl[s4 + 0][dd] = v.x; xl[s4 + 1][dd] = v.y;
      xl[s4 + 2][dd] = v.z; xl[s4 + 3][dd] = v.w;
    }
  }
  __syncthreads();
  const int wv = t >> 6, lane = t & 63;
  for (int rr = 0; rr < 4; ++rr) {
    const int srow = (wv << 2) + rr;
    const int n = s0 + srow;
    const unsigned long long mypk = (lane < 16) ? pkey[(size_t)n * 16 + lane] : ~0ULL;
    unsigned long long key = mypk;
#pragma unroll
    for (int mm = 1; mm < 64; mm <<= 1) {
      const unsigned long long o = __shfl_xor(key, mm, 64);
      key = o < key ? o : key;
    }
    const float v1 = dec_f((unsigned)(key >> 32));
    const unsigned ue = (__float_as_uint(v1) >> 23) & 0xffu;
    const float ulp = __uint_as_float((ue - 23) << 23);
    const float w = v1 + 2.0f * ulp + 3e-3f;
    unsigned qmask = (unsigned)(__ballot(dec_f((unsigned)(mypk >> 32)) <= w) & 0xffffULL);
    const float rn = rownorm[n];
    const float4 xv = *(const float4*)(&xl[srow][lane << 2]);
    unsigned long long best = ~0ULL;
    while (qmask) {
      const int T = __ffs(qmask) - 1;
      qmask &= qmask - 1;
      const float dval = dist[(size_t)n * 1024 + T * 64 + lane];
      unsigned long long cm = __ballot(dval <= w);
      while (cm) {
        const int l2 = __ffsll(cm) - 1;
        cm &= cm - 1;
        const int kk = T * 64 + l2;
        const float4 ev = *(const float4*)(emb + ((size_t)kk << 8) + (lane << 2));
        double p = (double)xv.x * ev.x + (double)xv.y * ev.y
                 + (double)xv.z * ev.z + (double)xv.w * ev.w;
#pragma unroll
        for (int mm = 1; mm < 64; mm <<= 1) p += __shfl_xor(p, mm, 64);
        const float dotf = (float)p;
        const float D = __fsub_rn(__fadd_rn(rn, embnorm[kk]), __fmul_rn(2.0f, dotf));
        const unsigned long long c = ((unsigned long long)enc_f(D) << 32) | (unsigned)kk;
        best = c < best ? c : best;
      }
    }
    const int bestk = (int)(best & 0xffffffffu);
    if (lane == 0) {
      bk_s[srow] = bestk;
      out[IDX_OFF + n] = (float)bestk;
      atomicAdd(&counts[bestk], 1.0f);
    }
  }
  __syncthreads();
  // z_q + loss phase: thread t owns dim d=t for all 16 rows
  const int d = t;
  float zq[16];
  float lsum = 0.f;
#pragma unroll
  for (int r2 = 0; r2 < 16; ++r2) {
    const float e = emb[((size_t)bk_s[r2] << 8) + d];
    const float z = xl[r2][d];
    const float df = __fsub_rn(e, z);
    zq[r2] = __fadd_rn(z, df);            // z + (z_q - z)
    lsum = fmaf(df, df, lsum);
  }
  float* op = out + ZQ_OFF + ((size_t)b << 18) + ((size_t)d << 10) + sb;
#pragma unroll
  for (int q = 0; q < 4; ++q)
    *(float4*)(op + (q << 2)) =
        make_float4(zq[q * 4], zq[q * 4 + 1], zq[q * 4 + 2], zq[q * 4 + 3]);
#pragma unroll
  for (int m = 32; m > 0; m >>= 1) lsum += __shfl_xor(lsum, m, 64);
  if (lane == 0) wredf[wv] = lsum;
  __syncthreads();
  if (t == 0) atomicAdd(lossacc, wredf[0] + wredf[1] + wredf[2] + wredf[3]);
}

__launch_bounds__(256)
__global__ void final_kernel(const float* __restrict__ counts, const float* __restrict__ lossacc,
                             float* __restrict__ out) {
  const int t = threadIdx.x;
  float ssum = 0.f;
#pragma unroll
  for (int u = 0; u < 4; ++u) {
    const float p = counts[t * 4 + u] * (1.0f / 32768.0f);
    ssum += p * logf(p + 1e-10f);
  }
#pragma unroll
  for (int m = 32; m > 0; m >>= 1) ssum += __shfl_xor(ssum, m, 64);
  __shared__ float wred[4];
  if ((t & 63) == 0) wred[t >> 6] = ssum;
  __syncthreads();
  if (t == 0) {
    const float tot = wred[0] + wred[1] + wred[2] + wred[3];
    out[PERP_OFF] = expf(-tot);
    const float mql = lossacc[0] * (1.0f / 8388608.0f);
    out[LOSS_OFF] = __fadd_rn(mql, __fmul_rn(0.25f, mql));
  }
}

extern "C" void kernel_launch(void* const* d_in, const int* in_sizes, int n_in,
                              void* d_out, int out_size, void* d_ws, size_t ws_size,
                              hipStream_t stream) {
  const float* z_e = (const float*)d_in[0];
  const float* emb = (const float*)d_in[1];
  float* out = (float*)d_out;
  char* ws = (char*)d_ws;

  unsigned short* ahi = (unsigned short*)(ws + WSB_AHI);
  unsigned short* bhi = (unsigned short*)(ws + WSB_BHI);
  float* rownorm = (float*)(ws + WSB_RN);
  float* embnorm = (float*)(ws + WSB_EN);
  unsigned long long* pkey = (unsigned long long*)(ws + WSB_PKEY);
  float* counts = (float*)(ws + WSB_CNT);
  float* lossacc = (float*)(ws + WSB_LOSS);

  hipMemsetAsync(ws + WSB_CNT, 0, 4100, stream);

  hipLaunchKernelGGL(prepE_kernel, dim3(132), dim3(256), 0, stream, emb, bhi, embnorm);
  hipLaunchKernelGGL(prep_kernel, dim3(256), dim3(256), 0, stream, z_e, ahi, rownorm);
  hipLaunchKernelGGL(dist_kernel, dim3(2048), dim3(256), 0, stream,
                     ahi, bhi, rownorm, embnorm, out + DIST_OFF, pkey);
  hipLaunchKernelGGL(rzq_kernel, dim3(2048), dim3(256), 0, stream,
                     z_e, emb, rownorm, embnorm, out + DIST_OFF, pkey, out, counts, lossacc);
  hipLaunchKernelGGL(final_kernel, dim3(1), dim3(256), 0, stream, counts, lossacc, out);
}